// Round 10
// baseline (280.581 us; speedup 1.0000x reference)
//
#include <hip/hip_runtime.h>
#include <hip/hip_fp16.h>

#define BB 4
#define CC 32
#define HH 480
#define WW 640
#define HWv (HH*WW)

typedef _Float16 f16x8 __attribute__((ext_vector_type(8)));
typedef _Float16 f16x2 __attribute__((ext_vector_type(2)));
typedef float f32x4 __attribute__((ext_vector_type(4)));

// ---- conv tile: 8 rows x 64 cols out, staged 10 x 72 x 32ch fp16 ----
#define CR 8
#define CCOL 64
#define SR 10
#define SC 72

// ---------------------------------------------------------------------------
// Kernel 1: 3x3 conv (32->8) + bias + normalization via fp16 MFMA
// implicit GEMM. Per 16-pixel group: 9 taps x mfma_f32_16x16x32_f16
// (A = 16px x 32ch from LDS, B = 32ch x 8outch weights in regs, C seeded
// with bias). Channels of D live in lanes n=0..7 -> normalization is a
// 3-shuffle reduce. Output transposed through reused LDS -> coalesced
// u32 stores of fp16 K.
// ---------------------------------------------------------------------------
__global__ __launch_bounds__(256, 2) void conv_mfma(const float* __restrict__ kx,
                                                    const float* __restrict__ Wf,
                                                    const float* __restrict__ bf,
                                                    _Float16* __restrict__ K)
{
    __shared__ _Float16 smem[SR * SC * CC];   // 46080 B

    const int t    = threadIdx.x;
    const int lane = t & 63;
    const int wv   = t >> 6;          // wave 0..3
    const int n    = lane & 15;       // B-col = out-channel; A-row = pixel
    const int ks   = lane >> 4;       // k-slice 0..3 (channels ks*8..+8)

    int blk = blockIdx.x;
    const int xt = blk % (WW / CCOL); blk /= (WW / CCOL);
    const int yt = blk % (HH / CR);
    const int b  = blk / (HH / CR);
    const int y0 = yt * CR;
    const int x0 = xt * CCOL;

    // ---- B fragments: lane holds W[o=n][c=ks*8+j][tap], n>=8 -> 0 ----
    f16x8 btap[9];
#pragma unroll
    for (int tp = 0; tp < 9; ++tp) {
#pragma unroll
        for (int j = 0; j < 8; ++j) {
            float w = (n < 8) ? Wf[(n * CC + (ks * 8 + j)) * 9 + tp] : 0.f;
            btap[tp][j] = (_Float16)w;
        }
    }
    const float bfv = (n < 8) ? bf[n] : 0.f;

    // ---- stage kx tile f32 -> f16, layout [y][x][c], XOR-swizzled ----
    const float* kxb = kx + (size_t)b * CC * HWv;
#pragma unroll
    for (int s = 0; s < 12; ++s) {
        int u = s * 256 + t;
        if (u < SR * SC * 4) {            // 2880 (x, y, ch-octet) units
            int xcol = u % SC;
            int yc   = u / SC;
            int yy   = yc >> 2;
            int co   = yc & 3;
            int gx = x0 - 4 + xcol;
            int gy = y0 - 1 + yy;
            bool ok = (gx >= 0) && (gx < WW) && (gy >= 0) && (gy < HH);
            const float* sp = kxb + (size_t)(co * 8) * HWv
                            + (size_t)(ok ? gy : 0) * WW + (ok ? gx : 0);
            f16x8 h;
#pragma unroll
            for (int j = 0; j < 8; ++j) {
                float v = ok ? sp[(size_t)j * HWv] : 0.f;
                h[j] = (_Float16)v;
            }
            int ba = ((yy * SC + xcol) * CC + co * 8) * 2;
            ba ^= ((xcol >> 1) & 7) << 4;
            *reinterpret_cast<f16x8*>(reinterpret_cast<char*>(smem) + ba) = h;
        }
    }
    __syncthreads();

    // ---- MFMA: 8 groups (2 rows x 4 col-groups per wave) x 9 taps ----
    f32x4 acc[8];
#pragma unroll
    for (int g = 0; g < 8; ++g) acc[g] = f32x4{bfv, bfv, bfv, bfv};

#pragma unroll
    for (int g = 0; g < 8; ++g) {
        int rl = wv * 2 + (g & 1);
        int xg = g >> 1;
#pragma unroll
        for (int ty = 0; ty < 3; ++ty) {
#pragma unroll
            for (int tx = 0; tx < 3; ++tx) {
                int xcol = xg * 16 + n + tx + 3;   // A-row pixel = lane&15
                int ba = (((rl + ty) * SC + xcol) * CC + ks * 8) * 2;
                ba ^= ((xcol >> 1) & 7) << 4;
                f16x8 a = *reinterpret_cast<const f16x8*>(
                              reinterpret_cast<const char*>(smem) + ba);
                acc[g] = __builtin_amdgcn_mfma_f32_16x16x32_f16(
                             a, btap[ty * 3 + tx], acc[g], 0, 0, 0);
            }
        }
    }
    __syncthreads();          // staged tile dead; reuse smem for output

    // ---- normalize (channels are lanes n=0..7) + LDS transpose ----
    _Float16* outa = smem;    // [512 px][10 planes]
#pragma unroll
    for (int g = 0; g < 8; ++g) {
        int rl = wv * 2 + (g & 1);
        int xg = g >> 1;
        float aff[4], sa[4], ss[4];
#pragma unroll
        for (int r = 0; r < 4; ++r) {
            aff[r] = (n < 8) ? acc[g][r] : 0.f;
            sa[r]  = fabsf(aff[r]);
            ss[r]  = aff[r];
        }
#pragma unroll
        for (int wdt = 1; wdt <= 4; wdt <<= 1) {
#pragma unroll
            for (int r = 0; r < 4; ++r) {
                sa[r] += __shfl_xor(sa[r], wdt);
                ss[r] += __shfl_xor(ss[r], wdt);
            }
        }
#pragma unroll
        for (int r = 0; r < 4; ++r) {
            float rinv = 1.0f / sa[r];
            float av   = aff[r] * rinv;
            float k0   = 1.0f - ss[r] * rinv;
            int px = rl * 64 + xg * 16 + ks * 4 + r;   // D row = (lane>>4)*4+reg
            if (n < 8)  outa[px * 10 + n + 1] = (_Float16)av;
            if (n == 0) outa[px * 10 + 0]     = (_Float16)k0;
        }
    }
    __syncthreads();

    // ---- coalesced store: 9 planes, 2 px (u32) per thread ----
    const int px0 = 2 * t;
    _Float16* Kb = K + (size_t)b * 9 * HWv
                 + (size_t)(y0 + (px0 >> 6)) * WW + x0 + (px0 & 63);
#pragma unroll
    for (int p = 0; p < 9; ++p) {
        f16x2 v2 = { outa[px0 * 10 + p], outa[(px0 + 1) * 10 + p] };
        *reinterpret_cast<f16x2*>(Kb + (size_t)p * HWv) = v2;
    }
}

// ---------------------------------------------------------------------------
// Kernel 2: one propagation iteration (R9 structure, fp16 K — proven).
// OFFSETS order: (0,0),(0,1),(0,-1),(1,0),(1,1),(1,-1),(-1,0),(-1,1),(-1,-1)
// ---------------------------------------------------------------------------
__device__ __forceinline__ void load_row6(const float* r, bool rowok, bool xm,
                                          bool xpl, float o[6])
{
    if (rowok) {
        float4 v = *reinterpret_cast<const float4*>(r);
        o[0] = xm ? r[-1] : 0.f;
        o[1] = v.x; o[2] = v.y; o[3] = v.z; o[4] = v.w;
        o[5] = xpl ? r[4] : 0.f;
    } else {
#pragma unroll
        for (int q = 0; q < 6; ++q) o[q] = 0.f;
    }
}

union H4 { short4 s; __half h[4]; };

__global__ __launch_bounds__(256) void prop(const float* __restrict__ xin,
                                            const __half* __restrict__ K,
                                            float* __restrict__ xout)
{
    int tid = blockIdx.x * 256 + threadIdx.x;
    const int XT = WW / 4;
    int x4 = tid % XT;
    int t2 = tid / XT;
    int y  = t2 % HH;
    int b  = t2 / HH;
    if (b >= BB) return;
    int x0 = x4 * 4;

    const bool xm  = (x0 > 0);
    const bool xpl = (x0 + 4 < WW);

    const float* xb = xin + (size_t)b * HWv + (size_t)y * WW + x0;
    float rm[6], r0[6], rp[6];
    load_row6(xb - WW, y > 0,      xm, xpl, rm);
    load_row6(xb,      true,       xm, xpl, r0);
    load_row6(xb + WW, y < HH - 1, xm, xpl, rp);

    const __half* Kb = K + (size_t)b * 9 * HWv + (size_t)y * WW + x0;
    float kv[9][4];
#pragma unroll
    for (int k = 0; k < 9; ++k) {
        H4 u;
        u.s = *reinterpret_cast<const short4*>(Kb + (size_t)k * HWv);  // 8 B
#pragma unroll
        for (int p = 0; p < 4; ++p) kv[k][p] = __half2float(u.h[p]);
    }

    float out[4];
#pragma unroll
    for (int p = 0; p < 4; ++p) {
        out[p] = kv[0][p] * r0[p + 1]
               + kv[1][p] * r0[p]
               + kv[2][p] * r0[p + 2]
               + kv[3][p] * rm[p + 1]
               + kv[4][p] * rm[p]
               + kv[5][p] * rm[p + 2]
               + kv[6][p] * rp[p + 1]
               + kv[7][p] * rp[p]
               + kv[8][p] * rp[p + 2];
    }

    *reinterpret_cast<float4*>(xout + (size_t)b * HWv + (size_t)y * WW + x0) =
        make_float4(out[0], out[1], out[2], out[3]);
}

// ---------------------------------------------------------------------------
extern "C" void kernel_launch(void* const* d_in, const int* in_sizes, int n_in,
                              void* d_out, int out_size, void* d_ws, size_t ws_size,
                              hipStream_t stream) {
    const float* kx   = (const float*)d_in[0];   // [4,32,480,640]
    const float* x_in = (const float*)d_in[1];   // [4,1,480,640]
    const float* Wf   = (const float*)d_in[2];   // [8,32,3,3]
    const float* bf   = (const float*)d_in[3];   // [8]
    float* out  = (float*)d_out;                 // [4,1,480,640]

    _Float16* Kbuf = (_Float16*)d_ws;                           // 22.1 MB fp16
    float*    xbuf = (float*)((char*)d_ws +
                              (size_t)9 * BB * HWv * sizeof(_Float16)); // 4.9 MB

    // conv: 2400 blocks x 256 threads (tile 8x64)
    const int cblocks = BB * (HH / CR) * (WW / CCOL);   // 2400
    conv_mfma<<<cblocks, 256, 0, stream>>>(kx, Wf, bf, Kbuf);

    // prop: 4 px/thread, block=256 -> 1200 blocks, 12 launches
    const int pthreads = BB * HH * (WW / 4);      // 307200
    const int pblocks  = pthreads / 256;          // 1200

    const float* src = x_in;
    for (int it = 0; it < 12; ++it) {
        float* dst = (it % 2 == 0) ? xbuf : out;  // it=11 (odd) -> d_out
        prop<<<pblocks, 256, 0, stream>>>(src, (const __half*)Kbuf, dst);
        src = dst;
    }
}

// Round 11
// 224.357 us; speedup vs baseline: 1.2506x; 1.2506x over previous
//
#include <hip/hip_runtime.h>
#include <hip/hip_fp16.h>

#define BB 4
#define CC 32
#define HH 480
#define WW 640
#define HWv (HH*WW)

// ---------------------------------------------------------------------------
// Kernel 1: 3x3 conv (32->8) + bias + affinity normalization, fused.
// R2/R9 compute structure, widened to 16 px/thread: doubles the FMA work
// (2304 cy) amortizing each channel-iteration's fixed stall budget
// (weight s_load lgkm waits + row-load latency), which measurement shows
// is TLP-invariant. K stored fp16 (proven R9).
// Output: K [B][9][H][W] fp16, K[0] = 1 - sum(a), K[1..8] = aff_k / sum|aff|
// ---------------------------------------------------------------------------
union H8 { __half h[8]; float4 f4; };

__global__ __launch_bounds__(64) void conv_gen(const float* __restrict__ kx,
                                               const float* __restrict__ Wf,
                                               const float* __restrict__ bf,
                                               __half* __restrict__ K)
{
    int tid = blockIdx.x * 64 + threadIdx.x;
    const int XT = WW / 16;             // 40 thread-columns
    int xg = tid % XT;
    int t2 = tid / XT;
    int y  = t2 % HH;
    int b  = t2 / HH;
    if (b >= BB) return;
    int x0 = xg * 16;

    float acc[8][16];
#pragma unroll
    for (int o = 0; o < 8; ++o) {
        float bv = bf[o];
#pragma unroll
        for (int p = 0; p < 16; ++p) acc[o][p] = bv;
    }

    const float* kxb = kx + (size_t)b * CC * HWv + (size_t)y * WW + x0;
    const bool xm = (x0 > 0);
    const bool xp = (x0 + 16 < WW);

    for (int c = 0; c < CC; ++c) {
        const float* pl = kxb + (size_t)c * HWv;
#pragma unroll
        for (int r = 0; r < 3; ++r) {
            const int dy = r - 1;
            const bool rowok = (y + dy >= 0) && (y + dy < HH);
            const float* rp = pl + dy * WW;
            float row[18];
            if (rowok) {
                float4 v0 = *reinterpret_cast<const float4*>(rp);
                float4 v1 = *reinterpret_cast<const float4*>(rp + 4);
                float4 v2 = *reinterpret_cast<const float4*>(rp + 8);
                float4 v3 = *reinterpret_cast<const float4*>(rp + 12);
                row[0]  = xm ? rp[-1] : 0.f;
                row[1]  = v0.x; row[2]  = v0.y; row[3]  = v0.z; row[4]  = v0.w;
                row[5]  = v1.x; row[6]  = v1.y; row[7]  = v1.z; row[8]  = v1.w;
                row[9]  = v2.x; row[10] = v2.y; row[11] = v2.z; row[12] = v2.w;
                row[13] = v3.x; row[14] = v3.y; row[15] = v3.z; row[16] = v3.w;
                row[17] = xp ? rp[16] : 0.f;
            } else {
#pragma unroll
                for (int q = 0; q < 18; ++q) row[q] = 0.f;
            }
#pragma unroll
            for (int o = 0; o < 8; ++o) {
#pragma unroll
                for (int t = 0; t < 3; ++t) {
                    // wave-uniform index -> s_load -> SGPR operand in v_fma
                    float wv = Wf[((o * CC + c) * 3 + r) * 3 + t];
#pragma unroll
                    for (int p = 0; p < 16; ++p) acc[o][p] += wv * row[p + t];
                }
            }
        }
    }

    // normalization: a = aff / sum|aff|; K0 = 1 - sum(a)
    float k0[16];
#pragma unroll
    for (int p = 0; p < 16; ++p) {
        float asum = 0.f;
#pragma unroll
        for (int o = 0; o < 8; ++o) asum += fabsf(acc[o][p]);
        float rinv = 1.0f / asum;
        float s = 0.f;
#pragma unroll
        for (int o = 0; o < 8; ++o) { acc[o][p] *= rinv; s += acc[o][p]; }
        k0[p] = 1.0f - s;
    }

    size_t base = (size_t)b * 9 * HWv + (size_t)y * WW + x0;   // element idx
    {
        H8 u0, u1;
#pragma unroll
        for (int p = 0; p < 8; ++p) { u0.h[p] = __float2half(k0[p]);
                                      u1.h[p] = __float2half(k0[p + 8]); }
        *reinterpret_cast<float4*>(K + base)     = u0.f4;
        *reinterpret_cast<float4*>(K + base + 8) = u1.f4;
    }
#pragma unroll
    for (int o = 0; o < 8; ++o) {
        H8 u0, u1;
#pragma unroll
        for (int p = 0; p < 8; ++p) { u0.h[p] = __float2half(acc[o][p]);
                                      u1.h[p] = __float2half(acc[o][p + 8]); }
        size_t pb = base + (size_t)(o + 1) * HWv;
        *reinterpret_cast<float4*>(K + pb)     = u0.f4;
        *reinterpret_cast<float4*>(K + pb + 8) = u1.f4;
    }
}

// ---------------------------------------------------------------------------
// Kernel 2: one propagation iteration (R9 structure, fp16 K — proven).
// OFFSETS order: (0,0),(0,1),(0,-1),(1,0),(1,1),(1,-1),(-1,0),(-1,1),(-1,-1)
// ---------------------------------------------------------------------------
__device__ __forceinline__ void load_row6(const float* r, bool rowok, bool xm,
                                          bool xpl, float o[6])
{
    if (rowok) {
        float4 v = *reinterpret_cast<const float4*>(r);
        o[0] = xm ? r[-1] : 0.f;
        o[1] = v.x; o[2] = v.y; o[3] = v.z; o[4] = v.w;
        o[5] = xpl ? r[4] : 0.f;
    } else {
#pragma unroll
        for (int q = 0; q < 6; ++q) o[q] = 0.f;
    }
}

union H4 { short4 s; __half h[4]; };

__global__ __launch_bounds__(256) void prop(const float* __restrict__ xin,
                                            const __half* __restrict__ K,
                                            float* __restrict__ xout)
{
    int tid = blockIdx.x * 256 + threadIdx.x;
    const int XT = WW / 4;
    int x4 = tid % XT;
    int t2 = tid / XT;
    int y  = t2 % HH;
    int b  = t2 / HH;
    if (b >= BB) return;
    int x0 = x4 * 4;

    const bool xm  = (x0 > 0);
    const bool xpl = (x0 + 4 < WW);

    const float* xb = xin + (size_t)b * HWv + (size_t)y * WW + x0;
    float rm[6], r0[6], rp[6];
    load_row6(xb - WW, y > 0,      xm, xpl, rm);
    load_row6(xb,      true,       xm, xpl, r0);
    load_row6(xb + WW, y < HH - 1, xm, xpl, rp);

    const __half* Kb = K + (size_t)b * 9 * HWv + (size_t)y * WW + x0;
    float kv[9][4];
#pragma unroll
    for (int k = 0; k < 9; ++k) {
        H4 u;
        u.s = *reinterpret_cast<const short4*>(Kb + (size_t)k * HWv);  // 8 B
#pragma unroll
        for (int p = 0; p < 4; ++p) kv[k][p] = __half2float(u.h[p]);
    }

    float out[4];
#pragma unroll
    for (int p = 0; p < 4; ++p) {
        out[p] = kv[0][p] * r0[p + 1]
               + kv[1][p] * r0[p]
               + kv[2][p] * r0[p + 2]
               + kv[3][p] * rm[p + 1]
               + kv[4][p] * rm[p]
               + kv[5][p] * rm[p + 2]
               + kv[6][p] * rp[p + 1]
               + kv[7][p] * rp[p]
               + kv[8][p] * rp[p + 2];
    }

    *reinterpret_cast<float4*>(xout + (size_t)b * HWv + (size_t)y * WW + x0) =
        make_float4(out[0], out[1], out[2], out[3]);
}

// ---------------------------------------------------------------------------
extern "C" void kernel_launch(void* const* d_in, const int* in_sizes, int n_in,
                              void* d_out, int out_size, void* d_ws, size_t ws_size,
                              hipStream_t stream) {
    const float* kx   = (const float*)d_in[0];   // [4,32,480,640]
    const float* x_in = (const float*)d_in[1];   // [4,1,480,640]
    const float* Wf   = (const float*)d_in[2];   // [8,32,3,3]
    const float* bf   = (const float*)d_in[3];   // [8]
    float* out  = (float*)d_out;                 // [4,1,480,640]

    __half* Kbuf = (__half*)d_ws;                               // 22.1 MB fp16
    float*  xbuf = (float*)((char*)d_ws +
                            (size_t)9 * BB * HWv * sizeof(__half));  // 4.9 MB

    // conv: 16 px/thread, block=64 -> 1200 blocks (1 wave each)
    const int cthreads = BB * HH * (WW / 16);     // 76800
    conv_gen<<<cthreads / 64, 64, 0, stream>>>(kx, Wf, bf, Kbuf);

    // prop: 4 px/thread, block=256 -> 1200 blocks, 12 launches
    const int pthreads = BB * HH * (WW / 4);      // 307200
    const int pblocks  = pthreads / 256;          // 1200

    const float* src = x_in;
    for (int it = 0; it < 12; ++it) {
        float* dst = (it % 2 == 0) ? xbuf : out;  // it=11 (odd) -> d_out
        prop<<<pblocks, 256, 0, stream>>>(src, Kbuf, dst);
        src = dst;
    }
}

// Round 12
// 168.832 us; speedup vs baseline: 1.6619x; 1.3289x over previous
//
#include <hip/hip_runtime.h>
#include <hip/hip_fp16.h>

#define BB 4
#define CC 32
#define HH 480
#define WW 640
#define HWv (HH*WW)

// ---- conv tiling: 8 rows x 128 cols, 256 threads (4 waves), 4 px/thread ----
#define TROWS 8
#define TCOLS 128
#define FR2 10                      // TROWS + 2 halo rows
#define FC2 144                     // TCOLS + 8 halo + padding (4-aligned)
#define BUFF 1536                   // 6 issues * 256 floats (>= 10*144 = 1440)

// ---------------------------------------------------------------------------
// Kernel 1: 3x3 conv (32->8) + bias + affinity normalization.
// R5-PROVEN sync structure (global_load_lds + __syncthreads double buffer),
// with its two measured flaws fixed:
//  (a) consume = 1 aligned ds_read_b128 + 2 scalars per row (~4-way
//      conflicts, vs 16-way / 3.3e7 in R5),
//  (b) 256 threads, 4 px/thread -> 4800 waves (4.7/SIMD) for latency hiding.
// Per channel-iter per wave: 576 FMA-cycles vs ~1.5 staging issues + ~120
// LDS-cycles -> load pressure finally << compute.
// Output: K [B][9][H][W] fp16 (proven R9).
// ---------------------------------------------------------------------------
union H4s { __half h[4]; short4 s4; };

__global__ __launch_bounds__(256) void conv_gen(const float* __restrict__ kx,
                                                const float* __restrict__ Wf,
                                                const float* __restrict__ bf,
                                                __half* __restrict__ K)
{
    __shared__ float lds[2 * BUFF];    // 12 KB

    const int t    = threadIdx.x;      // 0..255
    const int lane = t & 63;
    const int wv   = t >> 6;           // wave 0..3
    const int tx   = t & 31;           // 4-px column group 0..31
    const int ty   = t >> 5;           // row in tile 0..7

    int blk = blockIdx.x;
    const int xt = blk % (WW / TCOLS); blk /= (WW / TCOLS);
    const int yt = blk % (HH / TROWS);
    const int b  = blk / (HH / TROWS);
    const int y0 = yt * TROWS;
    const int x0 = xt * TCOLS;

    const float* kxb = kx + (size_t)b * CC * HWv;

    // ---- staging plan: 6 issues of 256 floats; waves 0,1 take 2, waves
    //      2,3 take 1. Per-lane clamped global sources (R5-proven scheme).
    const int nIss = (wv < 2) ? 2 : 1;
    int srcoff[2];
    int dstbase[2];
#pragma unroll
    for (int j = 0; j < 2; ++j) {
        int issue = (wv < 2) ? (2 * wv + j) : (2 + wv);   // 0..5
        int f  = issue * 256 + lane * 4;   // flat float index in fetch region
        int fr = f / FC2;
        int fc = f - fr * FC2;             // multiple of 4
        int rg = y0 - 1 + fr; rg = rg < 0 ? 0 : (rg > HH - 1 ? HH - 1 : rg);
        int cg = x0 - 4 + fc; cg = cg < 0 ? 0 : (cg > WW - 4 ? WW - 4 : cg);
        srcoff[j]  = rg * WW + cg;
        dstbase[j] = issue * 256;
    }

    // ---- channel-invariant boundary masks ----
    const float xmf = (x0 + 4 * tx     > 0 ) ? 1.f : 0.f;   // left halo valid
    const float xpf = (x0 + 4 * tx + 4 < WW) ? 1.f : 0.f;   // right halo valid
    float ml0[3], mc0[3], mr0[3];
#pragma unroll
    for (int r = 0; r < 3; ++r) {
        int ry = y0 + ty + r - 1;
        float ok = (ry >= 0 && ry < HH) ? 1.f : 0.f;
        mc0[r] = ok; ml0[r] = ok * xmf; mr0[r] = ok * xpf;
    }

    float acc[8][4];
#pragma unroll
    for (int o = 0; o < 8; ++o) {
        float bv = bf[o];
#pragma unroll
        for (int p = 0; p < 4; ++p) acc[o][p] = bv;
    }

    // ---- async stage: width-16 global_load_lds, linear LDS dest ----
    auto stage = [&](int c, int buf) {
        const float* src = kxb + (size_t)c * HWv;
#pragma unroll
        for (int j = 0; j < 2; ++j) {
            if (j < nIss) {
                float* dst = &lds[buf * BUFF + dstbase[j]];
                __builtin_amdgcn_global_load_lds(
                    (const __attribute__((address_space(1))) void*)(src + srcoff[j]),
                    (__attribute__((address_space(3))) void*)dst, 16, 0, 0);
            }
        }
    };

    stage(0, 0);
    __syncthreads();                       // drain prologue stage

#pragma unroll 1
    for (int c = 0; c < CC; ++c) {
        if (c + 1 < CC) stage(c + 1, (c + 1) & 1);   // prefetch next channel

        const float* bufp = &lds[(c & 1) * BUFF];
        float row[3][6];
#pragma unroll
        for (int r = 0; r < 3; ++r) {
            // fetch-region cols 4tx+3 .. 4tx+8  (global x-1 .. x+4)
            const float* rp = bufp + (ty + r) * FC2 + 4 * tx + 3;
            float4 va = *reinterpret_cast<const float4*>(rp + 1);  // 16B-aligned
            row[r][0] = rp[0] * ml0[r];
            row[r][1] = va.x * mc0[r]; row[r][2] = va.y * mc0[r];
            row[r][3] = va.z * mc0[r]; row[r][4] = va.w * mc0[r];
            row[r][5] = rp[5] * mr0[r];
        }

        const float* wc = Wf + c * 9;
#pragma unroll
        for (int o = 0; o < 8; ++o) {
#pragma unroll
            for (int r = 0; r < 3; ++r) {
#pragma unroll
                for (int s = 0; s < 3; ++s) {
                    float wvv = wc[o * (CC * 9) + r * 3 + s];  // uniform -> s_load
#pragma unroll
                    for (int p = 0; p < 4; ++p) acc[o][p] += wvv * row[r][p + s];
                }
            }
        }

        __syncthreads();   // drains stage(c+1) + fences buf reuse (R5-proven)
    }

    // ---- normalization: a = aff / sum|aff|; K0 = 1 - sum(a) ----
    float k0[4];
#pragma unroll
    for (int p = 0; p < 4; ++p) {
        float asum = 0.f;
#pragma unroll
        for (int o = 0; o < 8; ++o) asum += fabsf(acc[o][p]);
        float rinv = 1.0f / asum;
        float s = 0.f;
#pragma unroll
        for (int o = 0; o < 8; ++o) { acc[o][p] *= rinv; s += acc[o][p]; }
        k0[p] = 1.0f - s;
    }

    size_t base = (size_t)b * 9 * HWv + (size_t)(y0 + ty) * WW + x0 + 4 * tx;
    {
        H4s u;
#pragma unroll
        for (int p = 0; p < 4; ++p) u.h[p] = __float2half(k0[p]);
        *reinterpret_cast<short4*>(K + base) = u.s4;            // 8 B store
    }
#pragma unroll
    for (int o = 0; o < 8; ++o) {
        H4s u;
#pragma unroll
        for (int p = 0; p < 4; ++p) u.h[p] = __float2half(acc[o][p]);
        *reinterpret_cast<short4*>(K + base + (size_t)(o + 1) * HWv) = u.s4;
    }
}

// ---------------------------------------------------------------------------
// Kernel 2: one propagation iteration (R9 structure, fp16 K — proven).
// OFFSETS order: (0,0),(0,1),(0,-1),(1,0),(1,1),(1,-1),(-1,0),(-1,1),(-1,-1)
// ---------------------------------------------------------------------------
__device__ __forceinline__ void load_row6(const float* r, bool rowok, bool xm,
                                          bool xpl, float o[6])
{
    if (rowok) {
        float4 v = *reinterpret_cast<const float4*>(r);
        o[0] = xm ? r[-1] : 0.f;
        o[1] = v.x; o[2] = v.y; o[3] = v.z; o[4] = v.w;
        o[5] = xpl ? r[4] : 0.f;
    } else {
#pragma unroll
        for (int q = 0; q < 6; ++q) o[q] = 0.f;
    }
}

union H4 { short4 s; __half h[4]; };

__global__ __launch_bounds__(256) void prop(const float* __restrict__ xin,
                                            const __half* __restrict__ K,
                                            float* __restrict__ xout)
{
    int tid = blockIdx.x * 256 + threadIdx.x;
    const int XT = WW / 4;
    int x4 = tid % XT;
    int t2 = tid / XT;
    int y  = t2 % HH;
    int b  = t2 / HH;
    if (b >= BB) return;
    int x0 = x4 * 4;

    const bool xm  = (x0 > 0);
    const bool xpl = (x0 + 4 < WW);

    const float* xb = xin + (size_t)b * HWv + (size_t)y * WW + x0;
    float rm[6], r0[6], rp[6];
    load_row6(xb - WW, y > 0,      xm, xpl, rm);
    load_row6(xb,      true,       xm, xpl, r0);
    load_row6(xb + WW, y < HH - 1, xm, xpl, rp);

    const __half* Kb = K + (size_t)b * 9 * HWv + (size_t)y * WW + x0;
    float kv[9][4];
#pragma unroll
    for (int k = 0; k < 9; ++k) {
        H4 u;
        u.s = *reinterpret_cast<const short4*>(Kb + (size_t)k * HWv);  // 8 B
#pragma unroll
        for (int p = 0; p < 4; ++p) kv[k][p] = __half2float(u.h[p]);
    }

    float out[4];
#pragma unroll
    for (int p = 0; p < 4; ++p) {
        out[p] = kv[0][p] * r0[p + 1]
               + kv[1][p] * r0[p]
               + kv[2][p] * r0[p + 2]
               + kv[3][p] * rm[p + 1]
               + kv[4][p] * rm[p]
               + kv[5][p] * rm[p + 2]
               + kv[6][p] * rp[p + 1]
               + kv[7][p] * rp[p]
               + kv[8][p] * rp[p + 2];
    }

    *reinterpret_cast<float4*>(xout + (size_t)b * HWv + (size_t)y * WW + x0) =
        make_float4(out[0], out[1], out[2], out[3]);
}

// ---------------------------------------------------------------------------
extern "C" void kernel_launch(void* const* d_in, const int* in_sizes, int n_in,
                              void* d_out, int out_size, void* d_ws, size_t ws_size,
                              hipStream_t stream) {
    const float* kx   = (const float*)d_in[0];   // [4,32,480,640]
    const float* x_in = (const float*)d_in[1];   // [4,1,480,640]
    const float* Wf   = (const float*)d_in[2];   // [8,32,3,3]
    const float* bf   = (const float*)d_in[3];   // [8]
    float* out  = (float*)d_out;                 // [4,1,480,640]

    __half* Kbuf = (__half*)d_ws;                               // 22.1 MB fp16
    float*  xbuf = (float*)((char*)d_ws +
                            (size_t)9 * BB * HWv * sizeof(__half));  // 4.9 MB

    // conv: 1200 blocks x 256 threads (tile 8x128, 4 px/thread)
    const int cblocks = BB * (HH / TROWS) * (WW / TCOLS);   // 1200
    conv_gen<<<cblocks, 256, 0, stream>>>(kx, Wf, bf, Kbuf);

    // prop: 4 px/thread, block=256 -> 1200 blocks, 12 launches
    const int pthreads = BB * HH * (WW / 4);      // 307200
    const int pblocks  = pthreads / 256;          // 1200

    const float* src = x_in;
    for (int it = 0; it < 12; ++it) {
        float* dst = (it % 2 == 0) ? xbuf : out;  // it=11 (odd) -> d_out
        prop<<<pblocks, 256, 0, stream>>>(src, Kbuf, dst);
        src = dst;
    }
}